// Round 5
// baseline (163.962 us; speedup 1.0000x reference)
//
#include <hip/hip_runtime.h>
#include <hip/hip_bf16.h>

// Problem constants (B=1 folded out)
constexpr int T = 8;     // frames
constexpr int C = 128;   // input channels
constexpr int N = 4096;  // H*W positions
constexpr int F = 64;    // feature dim

typedef __bf16 bf16x8 __attribute__((ext_vector_type(8)));
typedef __bf16 bf16x4 __attribute__((ext_vector_type(4)));
typedef __bf16 bf16x2 __attribute__((ext_vector_type(2)));
typedef float  f32x4  __attribute__((ext_vector_type(4)));
typedef float  f32x16 __attribute__((ext_vector_type(16)));

// ---------------------------------------------------------------------------
// Kernel 1: projections + fused zero-out + in-register W conversion.
//   Q,K: D[m=f][n'=n] = W · X^T -> [n][F], b64 stores over f
//   G:   D[m=n][n'=f] = X^T · W3 -> [f][N], b64 stores over n
// W1/W2/W3 are read as f32 straight from L2 (96 KB total, hot after the
// first blocks) and converted to bf16 fragments in registers — numerically
// identical to the old prep_w kernel (same RNE cast). Each block also zeros
// its slice of d_out (attn accumulates into it with atomics).
// ---------------------------------------------------------------------------
__global__ __launch_bounds__(256) void proj_kernel(
    const float* __restrict__ x1, const float* __restrict__ x2,
    const float* __restrict__ W1, const float* __restrict__ W2,
    const float* __restrict__ W3,
    const float* __restrict__ b1, const float* __restrict__ b2,
    const float* __restrict__ b3,
    __bf16* __restrict__ Qb, __bf16* __restrict__ Kb, __bf16* __restrict__ Gw,
    float* __restrict__ out)
{
    const int t  = blockIdx.x >> 6;
    const int nb = blockIdx.x & 63;
    const int n0 = nb * 64;

    constexpr int XS = 136;           // 272B rows (16B aligned)
    __shared__ __bf16 Xt1[64 * XS];   // X1^T tile: [n_local][c]
    __shared__ __bf16 Xt2[64 * XS];

    const int tid = threadIdx.x;

    // ---- fused zero of d_out: 512 blocks x 256 threads x 4 f32x4 = 8.4 MB
    {
        f32x4* o4 = (f32x4*)out;
        const int base = blockIdx.x * 256 + tid;   // 131072 threads
#pragma unroll
        for (int i = 0; i < 4; ++i)
            o4[base + i * 131072] = (f32x4){0.f, 0.f, 0.f, 0.f};
    }

    const int ng  = tid & 15;         // n-block: n = ng*4 + j
    const int cgi = tid >> 4;         // c-group: c = cgi*4 (+64 per pass)

#pragma unroll
    for (int pass = 0; pass < 2; ++pass) {
        const int c0 = cgi * 4 + pass * 64;
        const size_t base = ((size_t)t * C + c0) * (size_t)N + n0 + ng * 4;
        f32x4 v1[4], v2[4];
#pragma unroll
        for (int i = 0; i < 4; ++i) {
            v1[i] = *(const f32x4*)&x1[base + (size_t)i * N];
            v2[i] = *(const f32x4*)&x2[base + (size_t)i * N];
        }
#pragma unroll
        for (int j = 0; j < 4; ++j) {
            bf16x4 o1, o2;
#pragma unroll
            for (int i = 0; i < 4; ++i) {
                o1[i] = (__bf16)v1[i][j];
                o2[i] = (__bf16)v2[i][j];
            }
            *(bf16x4*)&Xt1[(ng * 4 + j) * XS + c0] = o1;
            *(bf16x4*)&Xt2[(ng * 4 + j) * XS + c0] = o2;
        }
    }
    __syncthreads();

    const int wave = tid >> 6, lane = tid & 63;
    const int quad = lane >> 4, l16 = lane & 15;

    bf16x8 a1[4], a2[4];
#pragma unroll
    for (int cc = 0; cc < 4; ++cc) {
        a1[cc] = *(const bf16x8*)&Xt1[(wave * 16 + l16) * XS + cc * 32 + quad * 8];
        a2[cc] = *(const bf16x8*)&Xt2[(wave * 16 + l16) * XS + cc * 32 + quad * 8];
    }

    // ---- Q and K: D[m=f][n'=n] = W · X^T ----
#pragma unroll
    for (int p = 0; p < 2; ++p) {
        const float* W    = p ? W2 : W1;
        const float* bias = p ? b2 : b1;
        __bf16*      O    = p ? Kb : Qb;

        f32x4 acc[4];
#pragma unroll
        for (int ft = 0; ft < 4; ++ft) acc[ft] = (f32x4){0.f, 0.f, 0.f, 0.f};
#pragma unroll
        for (int cc = 0; cc < 4; ++cc) {
#pragma unroll
            for (int ft = 0; ft < 4; ++ft) {
                const float* ws = &W[(ft * 16 + l16) * C + cc * 32 + quad * 8];
                f32x4 w0 = *(const f32x4*)ws;
                f32x4 w1 = *(const f32x4*)(ws + 4);
                bf16x8 wf;
#pragma unroll
                for (int j = 0; j < 4; ++j) {
                    wf[j]     = (__bf16)w0[j];
                    wf[j + 4] = (__bf16)w1[j];
                }
                bf16x8 xf = p ? a2[cc] : a1[cc];
                acc[ft] = __builtin_amdgcn_mfma_f32_16x16x32_bf16(wf, xf, acc[ft], 0, 0, 0);
            }
        }
        const int n = n0 + wave * 16 + l16;
#pragma unroll
        for (int ft = 0; ft < 4; ++ft) {
            const int f0 = ft * 16 + quad * 4;
            f32x4 bv = *(const f32x4*)&bias[f0];
            bf16x4 o;
#pragma unroll
            for (int r = 0; r < 4; ++r) o[r] = (__bf16)(acc[ft][r] + bv[r]);
            *(bf16x4*)&O[((size_t)t * N + n) * F + f0] = o;
        }
    }

    // ---- G: D[m=n][n'=f] = X^T · W3 ----
    {
        f32x4 acc[4];
#pragma unroll
        for (int ft = 0; ft < 4; ++ft) acc[ft] = (f32x4){0.f, 0.f, 0.f, 0.f};
#pragma unroll
        for (int cc = 0; cc < 4; ++cc) {
#pragma unroll
            for (int ft = 0; ft < 4; ++ft) {
                const float* ws = &W3[(ft * 16 + l16) * C + cc * 32 + quad * 8];
                f32x4 w0 = *(const f32x4*)ws;
                f32x4 w1 = *(const f32x4*)(ws + 4);
                bf16x8 wf;
#pragma unroll
                for (int j = 0; j < 4; ++j) {
                    wf[j]     = (__bf16)w0[j];
                    wf[j + 4] = (__bf16)w1[j];
                }
                acc[ft] = __builtin_amdgcn_mfma_f32_16x16x32_bf16(a1[cc], wf, acc[ft], 0, 0, 0);
            }
        }
        const int nr0 = n0 + wave * 16 + quad * 4;
#pragma unroll
        for (int ft = 0; ft < 4; ++ft) {
            const int f = ft * 16 + l16;
            const float bv = b3[f];
            bf16x4 o;
#pragma unroll
            for (int r = 0; r < 4; ++r) o[r] = (__bf16)(acc[ft][r] + bv);
            *(bf16x4*)&Gw[((size_t)t * F + f) * (size_t)N + nr0] = o;
        }
    }
}

// ---------------------------------------------------------------------------
// Kernel 2: O[t][f][q] += sum_key relu(Q[q]·K[key]) * G[key][f]
//
// v4: double-buffered LDS, ONE barrier per 64-key iteration (T3-minimum
// pipeline). Iteration i: write regs(tile i+1) -> buf[i^1] (vmcnt wait lands
// on loads issued a full iteration earlier), issue loads(tile i+2), compute
// from buf[i], barrier. In-register S path (verified r4): 32x32x16 MFMA,
// relu+pack to bf16, v_permlane32_swap into PV B-frags; bank conflicts = 0.
// s_setprio(1) around MFMA clusters (T5).
// ---------------------------------------------------------------------------
constexpr int KSPLIT = 4;

__global__ __launch_bounds__(256) void attn_kernel(
    const __bf16* __restrict__ Qb, const __bf16* __restrict__ Kb,
    const __bf16* __restrict__ Gw, float* __restrict__ out)
{
    const int ks = blockIdx.x & (KSPLIT - 1);
    const int qb = (blockIdx.x / KSPLIT) & 31;   // N/128 = 32 q-blocks
    const int t  = blockIdx.x / (KSPLIT * 32);
    const int q0 = qb * 128;

    constexpr int KS = 72;                 // bf16 stride (144B rows)
    __shared__ __bf16 Kt[2][64 * KS];      // K tile [key][f], double-buffered
    __shared__ __bf16 Gt[2][64 * KS];      // G tile [f][key], double-buffered

    const int tid = threadIdx.x, wave = tid >> 6, lane = tid & 63;
    const int m32 = lane & 31, hi = lane >> 5;

    // Q B-frags (32x32x16): lane holds Q[q = q0+wave*32+m32][f = fc*16+hi*8+j]
    bf16x8 qf[4];
    {
        const __bf16* qrow = &Qb[((size_t)t * N + q0 + wave * 32 + m32) * F + hi * 8];
#pragma unroll
        for (int fc = 0; fc < 4; ++fc)
            qf[fc] = *(const bf16x8*)(qrow + fc * 16);
    }

    f32x16 oacc[2];   // [f-tile]; D: col=q=m32, row=f=ft*32+(r&3)+8*(r>>2)+4*hi
#pragma unroll
    for (int ft = 0; ft < 2; ++ft)
#pragma unroll
        for (int r = 0; r < 16; ++r) oacc[ft][r] = 0.f;

    const int kb_lo = ks * (N / 64 / KSPLIT);
    const int kb_hi = kb_lo + (N / 64 / KSPLIT);

    // staging unit: u in {tid, tid+256}; r8 = u>>3 (row), c8 = (u&7)*8 (col)
    const int r8a = tid >> 3,          c8a = (tid & 7) * 8;
    const int r8b = (tid + 256) >> 3,  c8b = c8a;

    bf16x8 kv0, kv1, gv0, gv1;

    // ---- prologue: load tile kb_lo, write buf0, issue loads for kb_lo+1
    {
        const int k0 = kb_lo * 64;
        kv0 = *(const bf16x8*)&Kb[((size_t)t * N + k0 + r8a) * F + c8a];
        kv1 = *(const bf16x8*)&Kb[((size_t)t * N + k0 + r8b) * F + c8b];
        gv0 = *(const bf16x8*)&Gw[((size_t)t * F + r8a) * (size_t)N + k0 + c8a];
        gv1 = *(const bf16x8*)&Gw[((size_t)t * F + r8b) * (size_t)N + k0 + c8b];
        *(bf16x8*)&Kt[0][r8a * KS + c8a] = kv0;
        *(bf16x8*)&Kt[0][r8b * KS + c8b] = kv1;
        *(bf16x8*)&Gt[0][r8a * KS + c8a] = gv0;
        *(bf16x8*)&Gt[0][r8b * KS + c8b] = gv1;
        const int k1 = k0 + 64;
        kv0 = *(const bf16x8*)&Kb[((size_t)t * N + k1 + r8a) * F + c8a];
        kv1 = *(const bf16x8*)&Kb[((size_t)t * N + k1 + r8b) * F + c8b];
        gv0 = *(const bf16x8*)&Gw[((size_t)t * F + r8a) * (size_t)N + k1 + c8a];
        gv1 = *(const bf16x8*)&Gw[((size_t)t * F + r8b) * (size_t)N + k1 + c8b];
    }
    __syncthreads();

    for (int kb = kb_lo; kb < kb_hi; ++kb) {
        const int cur = (kb - kb_lo) & 1;

        if (kb + 1 < kb_hi) {
            // write next tile (regs loaded a full iteration ago) to other buf
            *(bf16x8*)&Kt[cur ^ 1][r8a * KS + c8a] = kv0;
            *(bf16x8*)&Kt[cur ^ 1][r8b * KS + c8b] = kv1;
            *(bf16x8*)&Gt[cur ^ 1][r8a * KS + c8a] = gv0;
            *(bf16x8*)&Gt[cur ^ 1][r8b * KS + c8b] = gv1;
            if (kb + 2 < kb_hi) {   // issue loads for tile kb+2
                const int k2 = (kb + 2) * 64;
                kv0 = *(const bf16x8*)&Kb[((size_t)t * N + k2 + r8a) * F + c8a];
                kv1 = *(const bf16x8*)&Kb[((size_t)t * N + k2 + r8b) * F + c8b];
                gv0 = *(const bf16x8*)&Gw[((size_t)t * F + r8a) * (size_t)N + k2 + c8a];
                gv1 = *(const bf16x8*)&Gw[((size_t)t * F + r8b) * (size_t)N + k2 + c8b];
            }
        }

        // ---- S + pack: per 32-key block, Sᵀ stays in registers ----
        bf16x8 ps[4];   // PV B-frags: ps[kt*2+kc] = keys kt*32+kc*16+hi*8+(0..7)
#pragma unroll
        for (int kt = 0; kt < 2; ++kt) {
            f32x16 s;
#pragma unroll
            for (int r = 0; r < 16; ++r) s[r] = 0.f;
            __builtin_amdgcn_s_setprio(1);
#pragma unroll
            for (int fc = 0; fc < 4; ++fc) {
                bf16x8 kf = *(const bf16x8*)&Kt[cur][(kt * 32 + m32) * KS + fc * 16 + hi * 8];
                s = __builtin_amdgcn_mfma_f32_32x32x16_bf16(kf, qf[fc], s, 0, 0, 0);
            }
            __builtin_amdgcn_s_setprio(0);
            unsigned P[8];
#pragma unroll
            for (int m = 0; m < 8; ++m) {
                union { bf16x2 h; unsigned u; } pk;
                pk.h[0] = (__bf16)fmaxf(s[2 * m], 0.f);
                pk.h[1] = (__bf16)fmaxf(s[2 * m + 1], 0.f);
                P[m] = pk.u;
            }
            asm("v_permlane32_swap_b32 %0, %1" : "+v"(P[0]), "+v"(P[2]));
            asm("v_permlane32_swap_b32 %0, %1" : "+v"(P[1]), "+v"(P[3]));
            asm("v_permlane32_swap_b32 %0, %1" : "+v"(P[4]), "+v"(P[6]));
            asm("v_permlane32_swap_b32 %0, %1" : "+v"(P[5]), "+v"(P[7]));
            union { unsigned u[4]; bf16x8 v; } lo, hiu;
            lo.u[0]  = P[0]; lo.u[1]  = P[1]; lo.u[2]  = P[2]; lo.u[3]  = P[3];
            hiu.u[0] = P[4]; hiu.u[1] = P[5]; hiu.u[2] = P[6]; hiu.u[3] = P[7];
            ps[kt * 2]     = lo.v;
            ps[kt * 2 + 1] = hiu.v;
        }

        // ---- PV: Oᵀ[f][q]; A = Gt rows (f), k-dim = keys ----
        __builtin_amdgcn_s_setprio(1);
#pragma unroll
        for (int ft = 0; ft < 2; ++ft)
#pragma unroll
            for (int kt = 0; kt < 2; ++kt)
#pragma unroll
                for (int kc = 0; kc < 2; ++kc) {
                    bf16x8 gfr = *(const bf16x8*)&Gt[cur][(ft * 32 + m32) * KS +
                                                          kt * 32 + kc * 16 + hi * 8];
                    oacc[ft] = __builtin_amdgcn_mfma_f32_32x32x16_bf16(
                        gfr, ps[kt * 2 + kc], oacc[ft], 0, 0, 0);
                }
        __builtin_amdgcn_s_setprio(0);

        if (kb + 1 < kb_hi) __syncthreads();
    }

    // Epilogue: f = ft*32+(r&3)+8*(r>>2)+4*hi, q = q0+wave*32+m32
    const int q = q0 + wave * 32 + m32;
#pragma unroll
    for (int ft = 0; ft < 2; ++ft)
#pragma unroll
        for (int r = 0; r < 16; ++r) {
            int f = ft * 32 + (r & 3) + 8 * (r >> 2) + 4 * hi;
            unsafeAtomicAdd(&out[((size_t)t * F + f) * (size_t)N + q], oacc[ft][r]);
        }
}

// ---------------------------------------------------------------------------
extern "C" void kernel_launch(void* const* d_in, const int* in_sizes, int n_in,
                              void* d_out, int out_size, void* d_ws, size_t ws_size,
                              hipStream_t stream) {
    const float* x1 = (const float*)d_in[0];
    const float* x2 = (const float*)d_in[1];
    const float* W1 = (const float*)d_in[2];
    const float* b1 = (const float*)d_in[3];
    const float* W2 = (const float*)d_in[4];
    const float* b2 = (const float*)d_in[5];
    const float* W3 = (const float*)d_in[6];
    const float* b3 = (const float*)d_in[7];
    float* out = (float*)d_out;

    __bf16* Qb = (__bf16*)d_ws;
    __bf16* Kb = Qb + (size_t)T * N * F;
    __bf16* Gw = Kb + (size_t)T * N * F;

    proj_kernel<<<dim3(T * (N / 64)), dim3(256), 0, stream>>>(
        x1, x2, W1, W2, W3, b1, b2, b3, Qb, Kb, Gw, out);
    attn_kernel<<<dim3(T * 32 * KSPLIT), dim3(256), 0, stream>>>(Qb, Kb, Gw, out);
}

// Round 6
// 155.877 us; speedup vs baseline: 1.0519x; 1.0519x over previous
//
#include <hip/hip_runtime.h>
#include <hip/hip_bf16.h>

// Problem constants (B=1 folded out)
constexpr int T = 8;     // frames
constexpr int C = 128;   // input channels
constexpr int N = 4096;  // H*W positions
constexpr int F = 64;    // feature dim

typedef __bf16 bf16x8 __attribute__((ext_vector_type(8)));
typedef __bf16 bf16x4 __attribute__((ext_vector_type(4)));
typedef __bf16 bf16x2 __attribute__((ext_vector_type(2)));
typedef float  f32x4  __attribute__((ext_vector_type(4)));
typedef float  f32x16 __attribute__((ext_vector_type(16)));

// ---------------------------------------------------------------------------
// Kernel 0 (fused): zero d_out (attn accumulates with atomics) + convert
// W1/W2/W3 (fp32 [F][C]) to bf16 packed [3][F][C]. Grid = 2048 blocks covers
// the T*F*N/4 float4 zero-stores; first 24576 threads also convert W.
// ---------------------------------------------------------------------------
__global__ __launch_bounds__(256) void setup_kernel(
    const float* __restrict__ W1, const float* __restrict__ W2,
    const float* __restrict__ W3, __bf16* __restrict__ Wb,
    float* __restrict__ out)
{
    int i = blockIdx.x * 256 + threadIdx.x;
    ((f32x4*)out)[i] = (f32x4){0.f, 0.f, 0.f, 0.f};
    if (i < 3 * F * C) {
        int p = i >> 13, r = i & 8191;
        const float* W = (p == 0) ? W1 : (p == 1) ? W2 : W3;
        Wb[i] = (__bf16)W[r];
    }
}

// ---------------------------------------------------------------------------
// Kernel 1: projections (verified in round 2/4, unchanged).
//   Q,K: D[m=f][n'=n] = W · X^T -> [n][F], b64 stores over f
//   G:   D[m=n][n'=f] = X^T · W3 -> [f][N], b64 stores over n
// ---------------------------------------------------------------------------
__global__ __launch_bounds__(256) void proj_kernel(
    const float* __restrict__ x1, const float* __restrict__ x2,
    const __bf16* __restrict__ Wb,
    const float* __restrict__ b1, const float* __restrict__ b2,
    const float* __restrict__ b3,
    __bf16* __restrict__ Qb, __bf16* __restrict__ Kb, __bf16* __restrict__ Gw)
{
    const int t  = blockIdx.x >> 6;
    const int nb = blockIdx.x & 63;
    const int n0 = nb * 64;

    constexpr int XS = 136;           // 272B rows (16B aligned)
    __shared__ __bf16 Xt1[64 * XS];   // X1^T tile: [n_local][c]
    __shared__ __bf16 Xt2[64 * XS];

    const int tid = threadIdx.x;
    const int ng  = tid & 15;         // n-block: n = ng*4 + j
    const int cgi = tid >> 4;         // c-group: c = cgi*4 (+64 per pass)

#pragma unroll
    for (int pass = 0; pass < 2; ++pass) {
        const int c0 = cgi * 4 + pass * 64;
        const size_t base = ((size_t)t * C + c0) * (size_t)N + n0 + ng * 4;
        f32x4 v1[4], v2[4];
#pragma unroll
        for (int i = 0; i < 4; ++i) {
            v1[i] = *(const f32x4*)&x1[base + (size_t)i * N];
            v2[i] = *(const f32x4*)&x2[base + (size_t)i * N];
        }
#pragma unroll
        for (int j = 0; j < 4; ++j) {
            bf16x4 o1, o2;
#pragma unroll
            for (int i = 0; i < 4; ++i) {
                o1[i] = (__bf16)v1[i][j];
                o2[i] = (__bf16)v2[i][j];
            }
            *(bf16x4*)&Xt1[(ng * 4 + j) * XS + c0] = o1;
            *(bf16x4*)&Xt2[(ng * 4 + j) * XS + c0] = o2;
        }
    }
    __syncthreads();

    const int wave = tid >> 6, lane = tid & 63;
    const int quad = lane >> 4, l16 = lane & 15;

    bf16x8 a1[4], a2[4];
#pragma unroll
    for (int cc = 0; cc < 4; ++cc) {
        a1[cc] = *(const bf16x8*)&Xt1[(wave * 16 + l16) * XS + cc * 32 + quad * 8];
        a2[cc] = *(const bf16x8*)&Xt2[(wave * 16 + l16) * XS + cc * 32 + quad * 8];
    }

    // ---- Q and K: D[m=f][n'=n] = W · X^T ----
#pragma unroll
    for (int p = 0; p < 2; ++p) {
        const __bf16* W    = Wb + (size_t)p * F * C;
        const float*  bias = p ? b2 : b1;
        __bf16*       O    = p ? Kb : Qb;

        f32x4 acc[4];
#pragma unroll
        for (int ft = 0; ft < 4; ++ft) acc[ft] = (f32x4){0.f, 0.f, 0.f, 0.f};
#pragma unroll
        for (int cc = 0; cc < 4; ++cc) {
#pragma unroll
            for (int ft = 0; ft < 4; ++ft) {
                bf16x8 wf = *(const bf16x8*)&W[(ft * 16 + l16) * C + cc * 32 + quad * 8];
                bf16x8 xf = p ? a2[cc] : a1[cc];
                acc[ft] = __builtin_amdgcn_mfma_f32_16x16x32_bf16(wf, xf, acc[ft], 0, 0, 0);
            }
        }
        const int n = n0 + wave * 16 + l16;
#pragma unroll
        for (int ft = 0; ft < 4; ++ft) {
            const int f0 = ft * 16 + quad * 4;
            f32x4 bv = *(const f32x4*)&bias[f0];
            bf16x4 o;
#pragma unroll
            for (int r = 0; r < 4; ++r) o[r] = (__bf16)(acc[ft][r] + bv[r]);
            *(bf16x4*)&O[((size_t)t * N + n) * F + f0] = o;
        }
    }

    // ---- G: D[m=n][n'=f] = X^T · W3 ----
    {
        const __bf16* W3b = Wb + (size_t)2 * F * C;
        f32x4 acc[4];
#pragma unroll
        for (int ft = 0; ft < 4; ++ft) acc[ft] = (f32x4){0.f, 0.f, 0.f, 0.f};
#pragma unroll
        for (int cc = 0; cc < 4; ++cc) {
#pragma unroll
            for (int ft = 0; ft < 4; ++ft) {
                bf16x8 wf = *(const bf16x8*)&W3b[(ft * 16 + l16) * C + cc * 32 + quad * 8];
                acc[ft] = __builtin_amdgcn_mfma_f32_16x16x32_bf16(a1[cc], wf, acc[ft], 0, 0, 0);
            }
        }
        const int nr0 = n0 + wave * 16 + quad * 4;
#pragma unroll
        for (int ft = 0; ft < 4; ++ft) {
            const int f = ft * 16 + l16;
            const float bv = b3[f];
            bf16x4 o;
#pragma unroll
            for (int r = 0; r < 4; ++r) o[r] = (__bf16)(acc[ft][r] + bv);
            *(bf16x4*)&Gw[((size_t)t * F + f) * (size_t)N + nr0] = o;
        }
    }
}

// ---------------------------------------------------------------------------
// Kernel 2: O[t][f][q] += sum_key relu(Q[q]·K[key]) * G[key][f]
//
// v5: R4's verified 2-barrier single-buffer structure + in-register S path,
// with 64 q PER WAVE (2 q-groups of 32). The kf/gfr LDS fragments are loaded
// once and reused for BOTH q-groups -> LDS reads per unit work halve:
// per wave-iter now 16 ds_read_b128 + 4 writes serving 32 MFMA (was 16).
// Per-CU demand: MFMA ~13.7us, LDS ~12.8us -> balanced at the MFMA roofline.
// Block 256 = 4 waves = 256 q; q-blocks = 16; KSPLIT=4 -> grid 512 (2/CU,
// 2 waves/SIMD at ~190 VGPR). S/pack/permlane path verified in R4.
// ---------------------------------------------------------------------------
constexpr int KSPLIT = 4;

__global__ __launch_bounds__(256, 2) void attn_kernel(
    const __bf16* __restrict__ Qb, const __bf16* __restrict__ Kb,
    const __bf16* __restrict__ Gw, float* __restrict__ out)
{
    const int ks = blockIdx.x & (KSPLIT - 1);
    const int qb = (blockIdx.x / KSPLIT) & 15;   // N/256 = 16 q-blocks
    const int t  = blockIdx.x / (KSPLIT * 16);
    const int q0 = qb * 256;

    constexpr int KS = 72;              // bf16 stride (144B rows, 16B aligned)
    __shared__ __bf16 Kt[64 * KS];      // K tile [key][f]
    __shared__ __bf16 Gt[64 * KS];      // G tile [f][key]

    const int tid = threadIdx.x, wave = tid >> 6, lane = tid & 63;
    const int m32 = lane & 31, hi = lane >> 5;

    // Q B-frags (32x32x16): qf[qg][fc] = Q[q0+wave*64+qg*32+m32][fc*16+hi*8+j]
    bf16x8 qf[2][4];
#pragma unroll
    for (int qg = 0; qg < 2; ++qg) {
        const __bf16* qrow =
            &Qb[((size_t)t * N + q0 + wave * 64 + qg * 32 + m32) * F + hi * 8];
#pragma unroll
        for (int fc = 0; fc < 4; ++fc)
            qf[qg][fc] = *(const bf16x8*)(qrow + fc * 16);
    }

    f32x16 oacc[2][2];  // [qg][ft]; D: col=q=m32, row=f=ft*32+(r&3)+8*(r>>2)+4*hi
#pragma unroll
    for (int qg = 0; qg < 2; ++qg)
#pragma unroll
        for (int ft = 0; ft < 2; ++ft)
#pragma unroll
            for (int r = 0; r < 16; ++r) oacc[qg][ft][r] = 0.f;

    const int kb_lo = ks * (N / 64 / KSPLIT);
    const int kb_hi = kb_lo + (N / 64 / KSPLIT);

    // staging unit: u in {tid, tid+256}; r8 = u>>3 (row), c8 = (u&7)*8 (col)
    const int r8a = tid >> 3,          c8a = (tid & 7) * 8;
    const int r8b = (tid + 256) >> 3,  c8b = c8a;

    // prefetch tile kb_lo into registers
    bf16x8 kv0, kv1, gv0, gv1;
    {
        const int k0 = kb_lo * 64;
        kv0 = *(const bf16x8*)&Kb[((size_t)t * N + k0 + r8a) * F + c8a];
        kv1 = *(const bf16x8*)&Kb[((size_t)t * N + k0 + r8b) * F + c8b];
        gv0 = *(const bf16x8*)&Gw[((size_t)t * F + r8a) * (size_t)N + k0 + c8a];
        gv1 = *(const bf16x8*)&Gw[((size_t)t * F + r8b) * (size_t)N + k0 + c8b];
    }

    for (int kb = kb_lo; kb < kb_hi; ++kb) {
        __syncthreads();   // previous tile's LDS reads done
        *(bf16x8*)&Kt[r8a * KS + c8a] = kv0;
        *(bf16x8*)&Kt[r8b * KS + c8b] = kv1;
        *(bf16x8*)&Gt[r8a * KS + c8a] = gv0;
        *(bf16x8*)&Gt[r8b * KS + c8b] = gv1;
        __syncthreads();

        if (kb + 1 < kb_hi) {   // prefetch next tile (overlaps with compute)
            const int k0 = (kb + 1) * 64;
            kv0 = *(const bf16x8*)&Kb[((size_t)t * N + k0 + r8a) * F + c8a];
            kv1 = *(const bf16x8*)&Kb[((size_t)t * N + k0 + r8b) * F + c8b];
            gv0 = *(const bf16x8*)&Gw[((size_t)t * F + r8a) * (size_t)N + k0 + c8a];
            gv1 = *(const bf16x8*)&Gw[((size_t)t * F + r8b) * (size_t)N + k0 + c8b];
        }

        // ---- S + pack: kf frags loaded once per kt, reused for both q-groups
        bf16x8 ps[2][4];  // [qg][kt*2+kc]: keys kt*32+kc*16+hi*8+(0..7)
#pragma unroll
        for (int kt = 0; kt < 2; ++kt) {
            bf16x8 kf[4];
#pragma unroll
            for (int fc = 0; fc < 4; ++fc)
                kf[fc] = *(const bf16x8*)&Kt[(kt * 32 + m32) * KS + fc * 16 + hi * 8];
#pragma unroll
            for (int qg = 0; qg < 2; ++qg) {
                f32x16 s;
#pragma unroll
                for (int r = 0; r < 16; ++r) s[r] = 0.f;
                __builtin_amdgcn_s_setprio(1);
#pragma unroll
                for (int fc = 0; fc < 4; ++fc)
                    s = __builtin_amdgcn_mfma_f32_32x32x16_bf16(kf[fc], qf[qg][fc], s, 0, 0, 0);
                __builtin_amdgcn_s_setprio(0);
                unsigned P[8];
#pragma unroll
                for (int m = 0; m < 8; ++m) {
                    union { bf16x2 h; unsigned u; } pk;
                    pk.h[0] = (__bf16)fmaxf(s[2 * m], 0.f);
                    pk.h[1] = (__bf16)fmaxf(s[2 * m + 1], 0.f);
                    P[m] = pk.u;
                }
                asm("v_permlane32_swap_b32 %0, %1" : "+v"(P[0]), "+v"(P[2]));
                asm("v_permlane32_swap_b32 %0, %1" : "+v"(P[1]), "+v"(P[3]));
                asm("v_permlane32_swap_b32 %0, %1" : "+v"(P[4]), "+v"(P[6]));
                asm("v_permlane32_swap_b32 %0, %1" : "+v"(P[5]), "+v"(P[7]));
                union { unsigned u[4]; bf16x8 v; } lo, hiu;
                lo.u[0]  = P[0]; lo.u[1]  = P[1]; lo.u[2]  = P[2]; lo.u[3]  = P[3];
                hiu.u[0] = P[4]; hiu.u[1] = P[5]; hiu.u[2] = P[6]; hiu.u[3] = P[7];
                ps[qg][kt * 2]     = lo.v;
                ps[qg][kt * 2 + 1] = hiu.v;
            }
        }

        // ---- PV: Oᵀ[f][q]; gfr loaded once, reused for both q-groups ----
        __builtin_amdgcn_s_setprio(1);
#pragma unroll
        for (int ft = 0; ft < 2; ++ft)
#pragma unroll
            for (int kt = 0; kt < 2; ++kt)
#pragma unroll
                for (int kc = 0; kc < 2; ++kc) {
                    bf16x8 gfr = *(const bf16x8*)&Gt[(ft * 32 + m32) * KS +
                                                     kt * 32 + kc * 16 + hi * 8];
#pragma unroll
                    for (int qg = 0; qg < 2; ++qg)
                        oacc[qg][ft] = __builtin_amdgcn_mfma_f32_32x32x16_bf16(
                            gfr, ps[qg][kt * 2 + kc], oacc[qg][ft], 0, 0, 0);
                }
        __builtin_amdgcn_s_setprio(0);
    }

    // Epilogue: f = ft*32+(r&3)+8*(r>>2)+4*hi, q = q0+wave*64+qg*32+m32
#pragma unroll
    for (int qg = 0; qg < 2; ++qg) {
        const int q = q0 + wave * 64 + qg * 32 + m32;
#pragma unroll
        for (int ft = 0; ft < 2; ++ft)
#pragma unroll
            for (int r = 0; r < 16; ++r) {
                int f = ft * 32 + (r & 3) + 8 * (r >> 2) + 4 * hi;
                unsafeAtomicAdd(&out[((size_t)t * F + f) * (size_t)N + q], oacc[qg][ft][r]);
            }
    }
}

// ---------------------------------------------------------------------------
extern "C" void kernel_launch(void* const* d_in, const int* in_sizes, int n_in,
                              void* d_out, int out_size, void* d_ws, size_t ws_size,
                              hipStream_t stream) {
    const float* x1 = (const float*)d_in[0];
    const float* x2 = (const float*)d_in[1];
    const float* W1 = (const float*)d_in[2];
    const float* b1 = (const float*)d_in[3];
    const float* W2 = (const float*)d_in[4];
    const float* b2 = (const float*)d_in[5];
    const float* W3 = (const float*)d_in[6];
    const float* b3 = (const float*)d_in[7];
    float* out = (float*)d_out;

    __bf16* Qb = (__bf16*)d_ws;
    __bf16* Kb = Qb + (size_t)T * N * F;
    __bf16* Gw = Kb + (size_t)T * N * F;
    __bf16* Wb = Gw + (size_t)T * N * F;

    setup_kernel<<<dim3(T * F * N / 4 / 256), dim3(256), 0, stream>>>(
        W1, W2, W3, Wb, out);
    proj_kernel<<<dim3(T * (N / 64)), dim3(256), 0, stream>>>(
        x1, x2, Wb, b1, b2, b3, Qb, Kb, Gw);
    attn_kernel<<<dim3(T * 16 * KSPLIT), dim3(256), 0, stream>>>(Qb, Kb, Gw, out);
}